// Round 7
// baseline (80.986 us; speedup 1.0000x reference)
//
#include <hip/hip_runtime.h>

// TemporalNorm: causal rolling-window (W=128) mean/var norm over time, per (b,d).
// x: [B,T,D] f32, weight/bias: [D] f32, out: [B,T,D] f32.
// Strategy: one 64-lane wave processes TWO independent time-chunks interleaved
// (dual scan state) so each chunk's compute hides the other's load latency.
constexpr int Bb  = 32;
constexpr int Tt  = 4096;
constexpr int Dd  = 256;
constexpr int Ww  = 128;
constexpr float EPSF = 1e-5f;

constexpr int CT  = 128;           // time chunk (W/CT=1 -> fetch stays 1.0x)
constexpr int NC  = Tt / CT;       // 32 chunks per batch
constexpr int NP  = NC / 2;        // 16 chunk-pairs per batch
constexpr int NWG = Bb * NP;       // 512 blocks, 64 threads each
constexpr int S4  = Dd / 4;        // float4 stride per time step (64)

typedef float f32x4 __attribute__((ext_vector_type(4)));

__global__ __launch_bounds__(64)
void TemporalNorm_kernel(const float* __restrict__ x,
                         const float* __restrict__ wgt,
                         const float* __restrict__ bia,
                         float* __restrict__ out) {
    // XCD-contiguous swizzle (NWG % 8 == 0 -> bijective).
    const int i  = blockIdx.x;
    const int lb = (i & 7) * (NWG / 8) + (i >> 3);
    const int b  = lb / NP;
    const int p  = lb % NP;
    const int d4 = threadIdx.x;          // float4 channel group (0..63)
    const int t0A = (2 * p) * CT;
    const int t0B = t0A + CT;

    const f32x4* __restrict__ xb = reinterpret_cast<const f32x4*>(x   + (size_t)b * Tt * Dd) + d4;
    f32x4*       __restrict__ ob = reinterpret_cast<f32x4*>      (out + (size_t)b * Tt * Dd) + d4;
    const f32x4 w4 = reinterpret_cast<const f32x4*>(wgt)[d4];
    const f32x4 b4 = reinterpret_cast<const f32x4*>(bia)[d4];

    float s1A[4] = {0,0,0,0}, s2A[4] = {0,0,0,0};
    float s1B[4] = {0,0,0,0}, s2B[4] = {0,0,0,0};

    const float rn = 1.0f / (float)Ww;   // exact (1/128)

    auto acc = [&](const f32x4& a, float* s1, float* s2) {
#pragma unroll
        for (int k = 0; k < 4; ++k) { s1[k] += a[k]; s2[k] += a[k] * a[k]; }
    };
    auto step4 = [&](const f32x4& a, const f32x4& o, float* s1, float* s2) -> f32x4 {
        f32x4 r;
#pragma unroll
        for (int k = 0; k < 4; ++k) {
            s1[k] += a[k] - o[k];
            s2[k] += a[k] * a[k] - o[k] * o[k];
            float loc = s1[k] * rn;
            float var = s2[k] * rn - loc * loc;
            r[k] = (a[k] - loc) * rsqrtf(var + EPSF) * w4[k] + b4[k];
        }
        return r;
    };
    auto grow4 = [&](const f32x4& a, float* s1, float* s2, float n) -> f32x4 {
        float rnv = 1.0f / n;
        f32x4 r;
#pragma unroll
        for (int k = 0; k < 4; ++k) {
            float loc = s1[k] * rnv;
            float var = s2[k] * rnv - loc * loc;
            r[k] = (a[k] - loc) * rsqrtf(var + EPSF) * w4[k] + b4[k];
        }
        return r;
    };

    if (p != 0) {
        // ---- both chunks steady: warm-up interleaved ----
        for (int t = 0; t < Ww; t += 4) {
            f32x4 aA[4], aB[4];
#pragma unroll
            for (int j = 0; j < 4; ++j) aA[j] = xb[(t0A - Ww + t + j) * S4];
#pragma unroll
            for (int j = 0; j < 4; ++j) aB[j] = xb[(t0B - Ww + t + j) * S4];
#pragma unroll
            for (int j = 0; j < 4; ++j) { acc(aA[j], s1A, s2A); acc(aB[j], s1B, s2B); }
        }
        // ---- main loops interleaved: B's compute hides A's load latency ----
        for (int t = 0; t < CT; t += 4) {
            f32x4 aA[4], oA[4], aB[4], oB[4];
#pragma unroll
            for (int j = 0; j < 4; ++j) aA[j] = xb[(t0A + t + j) * S4];
#pragma unroll
            for (int j = 0; j < 4; ++j) oA[j] = xb[(t0A + t + j - Ww) * S4];
#pragma unroll
            for (int j = 0; j < 4; ++j) aB[j] = xb[(t0B + t + j) * S4];
#pragma unroll
            for (int j = 0; j < 4; ++j) oB[j] = xb[(t0B + t + j - Ww) * S4];
#pragma unroll
            for (int j = 0; j < 4; ++j) {
                f32x4 rA = step4(aA[j], oA[j], s1A, s2A);
                __builtin_nontemporal_store(rA, &ob[(t0A + t + j) * S4]);
            }
#pragma unroll
            for (int j = 0; j < 4; ++j) {
                f32x4 rB = step4(aB[j], oB[j], s1B, s2B);
                __builtin_nontemporal_store(rB, &ob[(t0B + t + j) * S4]);
            }
        }
    } else {
        // ---- pair (chunk0 growing, chunk1 steady) ----
        // chunk1's warm-up range IS chunk0's main data: load once, use twice.
        for (int t = 0; t < CT; t += 4) {
            f32x4 a[4];
#pragma unroll
            for (int j = 0; j < 4; ++j) a[j] = xb[(t + j) * S4];
#pragma unroll
            for (int j = 0; j < 4; ++j) {
                acc(a[j], s1A, s2A);                       // growing window
                f32x4 r = grow4(a[j], s1A, s2A, (float)(t + j + 1));
                __builtin_nontemporal_store(r, &ob[(t + j) * S4]);
                acc(a[j], s1B, s2B);                       // doubles as B warm-up
            }
        }
        // chunk1 main (solo)
        for (int t = 0; t < CT; t += 4) {
            f32x4 aB[4], oB[4];
#pragma unroll
            for (int j = 0; j < 4; ++j) aB[j] = xb[(t0B + t + j) * S4];
#pragma unroll
            for (int j = 0; j < 4; ++j) oB[j] = xb[(t0B + t + j - Ww) * S4];
#pragma unroll
            for (int j = 0; j < 4; ++j) {
                f32x4 rB = step4(aB[j], oB[j], s1B, s2B);
                __builtin_nontemporal_store(rB, &ob[(t0B + t + j) * S4]);
            }
        }
    }
}

extern "C" void kernel_launch(void* const* d_in, const int* in_sizes, int n_in,
                              void* d_out, int out_size, void* d_ws, size_t ws_size,
                              hipStream_t stream) {
    const float* x   = (const float*)d_in[0];
    const float* wgt = (const float*)d_in[1];
    const float* bia = (const float*)d_in[2];
    float* out = (float*)d_out;

    hipLaunchKernelGGL(TemporalNorm_kernel, dim3(NWG), dim3(64), 0, stream,
                       x, wgt, bia, out);
}

// Round 8
// 70.396 us; speedup vs baseline: 1.1504x; 1.1504x over previous
//
#include <hip/hip_runtime.h>
#include <cstdint>

// TemporalNorm: causal rolling-window (W=128) mean/var norm over time, per (b,d).
// x: [B,T,D] f32, weight/bias: [D] f32, out: [B,T,D] f32.
//
// R8: async global->LDS staging (global_load_lds w16) with counted vmcnt waits.
// 64-thread blocks; block owns (b, 64-channel dgroup, 256-t chunk).
// A-ring (3 slots): rows [t0-W, t0+CT) in 16-row batches (24 batches).
// O-ring (2 slots): rows [t0-W, t0+CT-W) (16 batches) - the o-subtract stream.
constexpr int Bb  = 32;
constexpr int Tt  = 4096;
constexpr int Dd  = 256;
constexpr int Ww  = 128;
constexpr float EPSF = 1e-5f;

constexpr int CT   = 256;            // outputs per block
constexpr int DG   = 64;             // channels per block
constexpr int NDG  = Dd / DG;        // 4
constexpr int NC   = Tt / CT;        // 16
constexpr int NWG  = Bb * NC * NDG;  // 2048 blocks = 8/CU exactly
constexpr int BATCH = 16;            // rows per batch (4 KB)
constexpr int WB   = Ww / BATCH;     // 8 warm batches
constexpr int MB   = CT / BATCH;     // 16 main batches

// s_waitcnt encodings (gfx9): vmcnt[3:0]@0, expcnt@4, lgkmcnt@8, vmcnt[5:4]@14
constexpr unsigned vm_enc(unsigned vm) {
    return (vm & 15u) | ((vm >> 4) << 14) | (7u << 4) | (15u << 8);
}
constexpr unsigned lgkm0_enc = 15u | (3u << 14) | (7u << 4) | (0u << 8);

#define SBAR() __builtin_amdgcn_sched_barrier(0)
#define WAITVM(n)  do { SBAR(); __builtin_amdgcn_s_waitcnt(vm_enc(n)); SBAR(); } while (0)
#define WAITLGKM() do { SBAR(); __builtin_amdgcn_s_waitcnt(lgkm0_enc); SBAR(); } while (0)

__global__ __launch_bounds__(64)
void TemporalNorm_kernel(const float* __restrict__ x,
                         const float* __restrict__ wgt,
                         const float* __restrict__ bia,
                         float* __restrict__ out) {
    __shared__ __align__(16) float Aring[3 * BATCH * DG];   // 12 KB
    __shared__ __align__(16) float Oring[2 * BATCH * DG];   //  8 KB

    // XCD-contiguous swizzle (NWG % 8 == 0 -> bijective).
    const int i  = blockIdx.x;
    const int lb = (i & 7) * (NWG / 8) + (i >> 3);
    const int dg   = lb % NDG;
    const int rest = lb / NDG;
    const int c = rest % NC;
    const int b = rest / NC;
    const int t0 = c * CT;

    const int lane = threadIdx.x;
    const int lrow = lane >> 4;            // row within 4-row stage group
    const int lcol = (lane & 15) * 4;      // float offset within 64-ch row

    const float wv = wgt[dg * DG + lane];
    const float bv = bia[dg * DG + lane];
    float* __restrict__ op = out + (size_t)b * Tt * Dd + dg * DG + lane;

    float s1 = 0.0f, s2 = 0.0f;
    const float rn = 1.0f / (float)Ww;

    if (c == 0) {
        // ---- chunk 0: growing window then steady; direct global loads ----
        const float* xp = x + (size_t)b * Tt * Dd + dg * DG + lane;
        for (int t = 0; t < Ww; t += 8) {
            float a[8];
#pragma unroll
            for (int j = 0; j < 8; ++j) a[j] = xp[(size_t)(t + j) * Dd];
#pragma unroll
            for (int j = 0; j < 8; ++j) {
                s1 += a[j]; s2 += a[j] * a[j];
                float rnv = 1.0f / (float)(t + j + 1);
                float loc = s1 * rnv;
                float var = s2 * rnv - loc * loc;
                op[(size_t)(t + j) * Dd] = (a[j] - loc) * rsqrtf(var + EPSF) * wv + bv;
            }
        }
        for (int t = Ww; t < CT; t += 8) {
            float a[8], o[8];
#pragma unroll
            for (int j = 0; j < 8; ++j) a[j] = xp[(size_t)(t + j) * Dd];
#pragma unroll
            for (int j = 0; j < 8; ++j) o[j] = xp[(size_t)(t + j - Ww) * Dd];
#pragma unroll
            for (int j = 0; j < 8; ++j) {
                s1 += a[j] - o[j];
                s2 += (a[j] - o[j]) * (a[j] + o[j]);
                float loc = s1 * rn;
                float var = s2 * rn - loc * loc;
                op[(size_t)(t + j) * Dd] = (a[j] - loc) * rsqrtf(var + EPSF) * wv + bv;
            }
        }
        return;
    }

    // ---- steady chunks (t0 >= 256 > W): pipelined LDS staging ----
    // Batch k rows: t0 - W + 16k. One global_load_lds(w16) stages 4 rows (1 KB).
    auto stageA = [&](int k) {
        const size_t rbase = (size_t)b * Tt + (t0 - Ww + BATCH * k);
        char* lds0 = (char*)Aring + (k % 3) * 4096;
#pragma unroll
        for (int j = 0; j < 4; ++j) {
            const float* g = x + (rbase + 4 * j + lrow) * Dd + dg * DG + lcol;
            __builtin_amdgcn_global_load_lds(
                (const __attribute__((address_space(1))) void*)g,
                (__attribute__((address_space(3))) void*)(lds0 + j * 1024), 16, 0, 0);
        }
    };
    auto stageO = [&](int k) {
        const size_t rbase = (size_t)b * Tt + (t0 - Ww + BATCH * k);
        char* lds0 = (char*)Oring + (k % 2) * 4096;
#pragma unroll
        for (int j = 0; j < 4; ++j) {
            const float* g = x + (rbase + 4 * j + lrow) * Dd + dg * DG + lcol;
            __builtin_amdgcn_global_load_lds(
                (const __attribute__((address_space(1))) void*)g,
                (__attribute__((address_space(3))) void*)(lds0 + j * 1024), 16, 0, 0);
        }
    };

    // Prologue: A0..A2 (12 instrs outstanding).
    stageA(0); stageA(1); stageA(2);
    SBAR();

    // Warm loop: consume A(w) (accumulate only), stage A(w+3); O0/O1 at w=6/7.
    for (int w = 0; w < WB; ++w) {
        WAITVM(8);                         // A(w) landed (A(w+1),A(w+2) in flight)
        const int as_ = (w % 3) * (BATCH * DG);
        float av[BATCH];
#pragma unroll
        for (int s = 0; s < BATCH; ++s) av[s] = Aring[as_ + s * DG + lane];
#pragma unroll
        for (int s = 0; s < BATCH; ++s) { float a = av[s]; s1 += a; s2 += a * a; }
        WAITLGKM();                        // ring reads done before overwrite
        stageA(w + 3);                     // A3..A10
        if (w == 6) stageO(0);
        if (w == 7) stageO(1);
        SBAR();
    }

    // Main loop m=0..15: consume A(8+m), O(m); stage A(11+m) (m<=12), O(2+m) (m<=13).
    // FIFO-derived waits: m0->8, m1..13->24, m14/15->16.
    for (int m = 0; m < MB; ++m) {
        if (m == 0)            WAITVM(8);
        else if (m >= 14)      WAITVM(16);
        else                   WAITVM(24);
        const int as_ = ((8 + m) % 3) * (BATCH * DG);
        const int os_ = (m % 2) * (BATCH * DG);
        float av[BATCH], ov[BATCH];
#pragma unroll
        for (int s = 0; s < BATCH; ++s) av[s] = Aring[as_ + s * DG + lane];
#pragma unroll
        for (int s = 0; s < BATCH; ++s) ov[s] = Oring[os_ + s * DG + lane];
#pragma unroll
        for (int s = 0; s < BATCH; ++s) {
            float a = av[s], o = ov[s];
            s1 += a - o;
            s2 += (a - o) * (a + o);
            float loc = s1 * rn;
            float var = s2 * rn - loc * loc;
            op[(size_t)(t0 + BATCH * m + s) * Dd] = (a - loc) * rsqrtf(var + EPSF) * wv + bv;
        }
        WAITLGKM();                        // ring reads done before overwrite
        if (m <= 12) stageA(11 + m);       // A11..A23
        if (m <= 13) stageO(2 + m);        // O2..O15
        SBAR();
    }
}

extern "C" void kernel_launch(void* const* d_in, const int* in_sizes, int n_in,
                              void* d_out, int out_size, void* d_ws, size_t ws_size,
                              hipStream_t stream) {
    const float* x   = (const float*)d_in[0];
    const float* wgt = (const float*)d_in[1];
    const float* bia = (const float*)d_in[2];
    float* out = (float*)d_out;

    hipLaunchKernelGGL(TemporalNorm_kernel, dim3(NWG), dim3(64), 0, stream,
                       x, wgt, bia, out);
}